// Round 7
// baseline (1367.334 us; speedup 1.0000x reference)
//
#include <hip/hip_runtime.h>

// TransformerBlock: B=8,S=196,D=768,H=12,HD=64,E=8,FF=3072. T = B*S = 1568.
//
// Exact simplifications:
//  - attention: k,v broadcast across heads -> softmax uniform -> attn_out=tile(v).
//    Wq/bq/Wk/bk/RoPE are dead code.
//  - MoE top-1 = argmax of gating logits (softmax monotone).
//
// R6: ONE persistent mega-kernel (768 blocks, guaranteed co-resident) with a
// device-scope grid barrier between phases:
//   P0 pre (LN1 + vproj-in-regs + x2/LN2 + gate + out init)
//   P1 gemm1 (h2 @ W1 + gelu -> hmid)        [work-stealing over item space]
//   P2 gemm2 (hmid @ W2, split-K x4 -> part)
//   P3 reduce (out += sum part)
// Kills the ~150us of inter-dispatch overhead/serialization/drain seen R1-R5.
// GEMM B-path: fp32 global (coalesced dword) -> bf16 LDS transposed, stride 66
// (b16 writes 2-way free; frag reads 4x conflict-free ds_read_b32). A: b128.

typedef unsigned short u16;
typedef short bf16x8_t __attribute__((ext_vector_type(8)));
typedef float f32x4_t  __attribute__((ext_vector_type(4)));

#define T_TOK 1568
#define DM 768
#define HD 64
#define FF 3072
#define NE 8
#define MT_MAX 13
#define NBLK 768

#define OFF_CNT   0         // 8 ints
#define OFF_BAR   64        // 4 ints
#define OFF_BUCK  128       // NE*T_TOK ints -> 50304
#define OFF_H2    50304     // T_TOK*DM u16  -> 2458752
#define OFF_HMID  2458752   // T_TOK*FF u16  -> 12092544
#define OFF_PART  12092544  // 4*T_TOK*DM f32 -> 31360128

__device__ __forceinline__ float bf2f(u16 h) {
    unsigned u = ((unsigned)h) << 16;
    return __builtin_bit_cast(float, u);
}
__device__ __forceinline__ u16 f2bf(float f) {  // RNE
    unsigned u = __builtin_bit_cast(unsigned, f);
    unsigned r = (u + 0x7FFFu + ((u >> 16) & 1u)) >> 16;
    return (u16)r;
}
__device__ __forceinline__ float gelu_f(float x) {
    return 0.5f * x * (1.0f + erff(x * 0.70710678118654752440f));
}
__device__ __forceinline__ void bar_lds() {
    asm volatile("s_waitcnt lgkmcnt(0)\n\ts_barrier" ::: "memory");
}
// device-scope grid barrier; all NBLK blocks co-resident by construction
__device__ __forceinline__ void gbar(int* bars, int idx) {
    __syncthreads();
    if (threadIdx.x == 0) {
        __threadfence();
        __hip_atomic_fetch_add(&bars[idx], 1, __ATOMIC_RELEASE, __HIP_MEMORY_SCOPE_AGENT);
        while (__hip_atomic_load(&bars[idx], __ATOMIC_ACQUIRE, __HIP_MEMORY_SCOPE_AGENT) < NBLK)
            __builtin_amdgcn_s_sleep(2);
    }
    __syncthreads();
}

union SMem {
    struct { float wgs[NE * DM]; float g2s[DM]; float b2s[DM]; } pre;   // 30.7 KB
    struct { u16 As[128 * 40]; u16 Bs[128 * 66]; } g;                   // 27.1 KB
};

__global__ __launch_bounds__(256, 3) void k_mega(
        const float* __restrict__ x,
        const float* __restrict__ g1, const float* __restrict__ b1v,
        const float* __restrict__ Wv, const float* __restrict__ bv,
        const float* __restrict__ g2, const float* __restrict__ b2g,
        const float* __restrict__ Wg, const float* __restrict__ bg,
        const float* __restrict__ W1, const float* __restrict__ b1m,
        const float* __restrict__ W2, const float* __restrict__ b2m,
        int* __restrict__ cnt, int* __restrict__ bars,
        int* __restrict__ buck, u16* __restrict__ h2,
        u16* __restrict__ hmid, float* __restrict__ part,
        float* __restrict__ out) {
    __shared__ SMem sm;
    int bid = blockIdx.x, tid = threadIdx.x, lane = tid & 63, wid = tid >> 6;

    // ================= P0: pre (392 blocks x 4 tokens, 1 token/wave) ==========
    if (bid < 392) {
        for (int idx = tid; idx < NE * DM; idx += 256) {
            int e = idx / DM, c = idx % DM;
            sm.pre.wgs[idx] = Wg[(size_t)c * NE + e];
        }
        for (int idx = tid; idx < DM; idx += 256) {
            sm.pre.g2s[idx] = g2[idx]; sm.pre.b2s[idx] = b2g[idx];
        }
        __syncthreads();
        int t = bid * 4 + wid;
        const float* xp = x + (size_t)t * DM;
        float xv[12], s = 0.0f;
#pragma unroll
        for (int i = 0; i < 12; i++) { xv[i] = xp[lane + 64 * i]; s += xv[i]; }
#pragma unroll
        for (int m = 1; m < 64; m <<= 1) s += __shfl_xor(s, m);
        float mu = s * (1.0f / DM), vs = 0.0f;
#pragma unroll
        for (int i = 0; i < 12; i++) { float d = xv[i] - mu; vs += d * d; }
#pragma unroll
        for (int m = 1; m < 64; m <<= 1) vs += __shfl_xor(vs, m);
        float rs = rsqrtf(vs * (1.0f / DM) + 1e-5f);
        float h1f[12];
#pragma unroll
        for (int i = 0; i < 12; i++) {
            int c = lane + 64 * i;
            h1f[i] = (xv[i] - mu) * rs * g1[c] + b1v[c];
        }
        // vproj: v[lane] = sum_c h1[c]*Wv[c][lane]  (shfl-broadcast h1)
        float va = 0.0f, vb = 0.0f;
        for (int i = 0; i < 12; i++) {
#pragma unroll
            for (int kk = 0; kk < 64; kk += 2) {
                va = fmaf(__shfl(h1f[i], kk),     Wv[(size_t)(i * 64 + kk) * 64 + lane], va);
                vb = fmaf(__shfl(h1f[i], kk + 1), Wv[(size_t)(i * 64 + kk + 1) * 64 + lane], vb);
            }
        }
        float vlane = va + vb + bv[lane];
        // x2 = x + tile(v): col c gets v[c%64] = v[lane]
        float x2v[12]; s = 0.0f;
#pragma unroll
        for (int i = 0; i < 12; i++) { x2v[i] = xv[i] + vlane; s += x2v[i]; }
#pragma unroll
        for (int m = 1; m < 64; m <<= 1) s += __shfl_xor(s, m);
        float mu2 = s * (1.0f / DM); vs = 0.0f;
#pragma unroll
        for (int i = 0; i < 12; i++) { float d = x2v[i] - mu2; vs += d * d; }
#pragma unroll
        for (int m = 1; m < 64; m <<= 1) vs += __shfl_xor(vs, m);
        float rs2 = rsqrtf(vs * (1.0f / DM) + 1e-5f);
        float le[NE];
#pragma unroll
        for (int e = 0; e < NE; e++) le[e] = 0.0f;
        u16* h2p = h2 + (size_t)t * DM;
#pragma unroll
        for (int i = 0; i < 12; i++) {
            int c = lane + 64 * i;
            float h = (x2v[i] - mu2) * rs2 * sm.pre.g2s[c] + sm.pre.b2s[c];
            h2p[c] = f2bf(h);
#pragma unroll
            for (int e = 0; e < NE; e++) le[e] += h * sm.pre.wgs[e * DM + c];
        }
#pragma unroll
        for (int e = 0; e < NE; e++) {
#pragma unroll
            for (int m = 1; m < 64; m <<= 1) le[e] += __shfl_xor(le[e], m);
        }
        float best = le[0] + bg[0]; int be = 0;
#pragma unroll
        for (int e = 1; e < NE; e++) {
            float qv = le[e] + bg[e];
            if (qv > best) { best = qv; be = e; }   // first-max == jnp.argmax
        }
        if (lane == 0) {
            int pos = atomicAdd(&cnt[be], 1);
            buck[be * T_TOK + pos] = t;
        }
        float* op = out + (size_t)t * DM;
        const float* bp = b2m + (size_t)be * DM;
#pragma unroll
        for (int i = 0; i < 12; i++) {
            int c = lane + 64 * i;
            op[c] = x2v[i] + bp[c];
        }
    }
    gbar(bars, 0);

    // common GEMM lane decode
    int wm = wid >> 1, wn = wid & 1, lr = lane & 15, q = lane >> 4;
    int ar = tid >> 2, ac4 = tid & 3;     // A rows ar, ar+64; 16B chunk ac4
    int nlo = tid & 63, wsel = tid >> 6;  // B: n base, k base

    // ================= P1: gemm1 hmid = gelu(h2 @ W1[e] + b1m[e]) =============
    for (int it = bid; it < NE * MT_MAX * 24; it += NBLK) {
        int e = it / (MT_MAX * 24), rem = it % (MT_MAX * 24);
        int mt = rem / 24, ntl = rem % 24;
        int cnte = cnt[e], m0 = mt * 128;
        if (m0 >= cnte) continue;
        int n0 = ntl * 128;
        const float* Bg = W1 + (size_t)e * DM * FF;
        int atok0, atok1;
        { int i0 = m0 + ar, i1 = m0 + ar + 64;
          atok0 = (i0 < cnte) ? buck[e * T_TOK + i0] : -1;
          atok1 = (i1 < cnte) ? buck[e * T_TOK + i1] : -1; }
        f32x4_t acc[4][4];
#pragma unroll
        for (int mi = 0; mi < 4; mi++)
#pragma unroll
            for (int ni = 0; ni < 4; ni++) acc[mi][ni] = (f32x4_t){0.f, 0.f, 0.f, 0.f};
        bf16x8_t pA[2]; float bp[16];
#define LD1(kk)                                                                \
        { bf16x8_t z = {0,0,0,0,0,0,0,0};                                      \
          pA[0] = (atok0 >= 0) ? *(const bf16x8_t*)&h2[(size_t)atok0 * DM + (kk) + ac4 * 8] : z; \
          pA[1] = (atok1 >= 0) ? *(const bf16x8_t*)&h2[(size_t)atok1 * DM + (kk) + ac4 * 8] : z; \
          _Pragma("unroll")                                                    \
          for (int j = 0; j < 16; j++)                                         \
              bp[j] = Bg[(size_t)((kk) + wsel + 4 * (j >> 1)) * FF + n0 + nlo + 64 * (j & 1)]; }
        LD1(0);
#pragma unroll 1
        for (int kt = 0; kt < 24; kt++) {
            bar_lds();
            *(bf16x8_t*)&sm.g.As[ar * 40 + ac4 * 8] = pA[0];
            *(bf16x8_t*)&sm.g.As[(ar + 64) * 40 + ac4 * 8] = pA[1];
#pragma unroll
            for (int j = 0; j < 16; j++)
                sm.g.Bs[(nlo + 64 * (j & 1)) * 66 + wsel + 4 * (j >> 1)] = f2bf(bp[j]);
            bar_lds();
            if (kt + 1 < 24) LD1((kt + 1) * 32);
            bf16x8_t af[4];
#pragma unroll
            for (int mi = 0; mi < 4; mi++)
                af[mi] = *(const bf16x8_t*)&sm.g.As[(wm * 64 + mi * 16 + lr) * 40 + q * 8];
#pragma unroll
            for (int ni = 0; ni < 4; ni++) {
                const int* b32 = (const int*)&sm.g.Bs[(wn * 64 + ni * 16 + lr) * 66 + q * 8];
                int4 pk = {b32[0], b32[1], b32[2], b32[3]};
                bf16x8_t bb = __builtin_bit_cast(bf16x8_t, pk);
#pragma unroll
                for (int mi = 0; mi < 4; mi++)
                    acc[mi][ni] = __builtin_amdgcn_mfma_f32_16x16x32_bf16(af[mi], bb, acc[mi][ni], 0, 0, 0);
            }
        }
#undef LD1
        float bias[4];
#pragma unroll
        for (int ni = 0; ni < 4; ni++)
            bias[ni] = b1m[(size_t)e * FF + n0 + wn * 64 + ni * 16 + lr];
#pragma unroll
        for (int mi = 0; mi < 4; mi++) {
#pragma unroll
            for (int r = 0; r < 4; r++) {
                int i = m0 + wm * 64 + mi * 16 + q * 4 + r;
                if (i < cnte) {
                    int t = buck[e * T_TOK + i];
                    size_t base = (size_t)t * FF + n0 + wn * 64;
#pragma unroll
                    for (int ni = 0; ni < 4; ni++)
                        hmid[base + ni * 16 + lr] = f2bf(gelu_f(acc[mi][ni][r] + bias[ni]));
                }
            }
        }
        bar_lds();   // protect LDS before next item's staging
    }
    gbar(bars, 1);

    // ================= P2: gemm2 part[kc] = hmid @ W2[e] (split-K x4) =========
    for (int it = bid; it < NE * MT_MAX * 4 * 6; it += NBLK) {
        int e = it / (MT_MAX * 24), rem = it % (MT_MAX * 24);
        int mt = rem / 24, r2 = rem % 24;
        int kc = r2 / 6, ntl = r2 % 6;
        int cnte = cnt[e], m0 = mt * 128;
        if (m0 >= cnte) continue;
        int n0 = ntl * 128, kbase = kc * (FF / 4);
        int off = 0;
        for (int ee = 0; ee < NE; ee++) off += (ee < e) ? cnt[ee] : 0;
        const float* Bg = W2 + (size_t)e * FF * DM;
        int atok0, atok1;
        { int i0 = m0 + ar, i1 = m0 + ar + 64;
          atok0 = (i0 < cnte) ? buck[e * T_TOK + i0] : -1;
          atok1 = (i1 < cnte) ? buck[e * T_TOK + i1] : -1; }
        f32x4_t acc[4][4];
#pragma unroll
        for (int mi = 0; mi < 4; mi++)
#pragma unroll
            for (int ni = 0; ni < 4; ni++) acc[mi][ni] = (f32x4_t){0.f, 0.f, 0.f, 0.f};
        bf16x8_t pA[2]; float bp[16];
#define LD2(kk)                                                                \
        { bf16x8_t z = {0,0,0,0,0,0,0,0};                                      \
          pA[0] = (atok0 >= 0) ? *(const bf16x8_t*)&hmid[(size_t)atok0 * FF + kbase + (kk) + ac4 * 8] : z; \
          pA[1] = (atok1 >= 0) ? *(const bf16x8_t*)&hmid[(size_t)atok1 * FF + kbase + (kk) + ac4 * 8] : z; \
          _Pragma("unroll")                                                    \
          for (int j = 0; j < 16; j++)                                         \
              bp[j] = Bg[(size_t)(kbase + (kk) + wsel + 4 * (j >> 1)) * DM + n0 + nlo + 64 * (j & 1)]; }
        LD2(0);
#pragma unroll 1
        for (int kt = 0; kt < 24; kt++) {
            bar_lds();
            *(bf16x8_t*)&sm.g.As[ar * 40 + ac4 * 8] = pA[0];
            *(bf16x8_t*)&sm.g.As[(ar + 64) * 40 + ac4 * 8] = pA[1];
#pragma unroll
            for (int j = 0; j < 16; j++)
                sm.g.Bs[(nlo + 64 * (j & 1)) * 66 + wsel + 4 * (j >> 1)] = f2bf(bp[j]);
            bar_lds();
            if (kt + 1 < 24) LD2((kt + 1) * 32);
            bf16x8_t af[4];
#pragma unroll
            for (int mi = 0; mi < 4; mi++)
                af[mi] = *(const bf16x8_t*)&sm.g.As[(wm * 64 + mi * 16 + lr) * 40 + q * 8];
#pragma unroll
            for (int ni = 0; ni < 4; ni++) {
                const int* b32 = (const int*)&sm.g.Bs[(wn * 64 + ni * 16 + lr) * 66 + q * 8];
                int4 pk = {b32[0], b32[1], b32[2], b32[3]};
                bf16x8_t bb = __builtin_bit_cast(bf16x8_t, pk);
#pragma unroll
                for (int mi = 0; mi < 4; mi++)
                    acc[mi][ni] = __builtin_amdgcn_mfma_f32_16x16x32_bf16(af[mi], bb, acc[mi][ni], 0, 0, 0);
            }
        }
#undef LD2
        float* pbase = part + (size_t)kc * T_TOK * DM;
#pragma unroll
        for (int mi = 0; mi < 4; mi++) {
#pragma unroll
            for (int r = 0; r < 4; r++) {
                int i = m0 + wm * 64 + mi * 16 + q * 4 + r;
                if (i < cnte) {
                    float* pp = pbase + (size_t)(off + i) * DM + n0 + wn * 64;
#pragma unroll
                    for (int ni = 0; ni < 4; ni++)
                        pp[ni * 16 + lr] = acc[mi][ni][r];
                }
            }
        }
        bar_lds();
    }
    gbar(bars, 2);

    // ================= P3: reduce out += sum_kc part[kc] ======================
    for (int it = bid; it < NE * MT_MAX * 6; it += NBLK) {
        int e = it / (MT_MAX * 6), rem = it % (MT_MAX * 6);
        int mt = rem / 6, ntl = rem % 6;
        int cnte = cnt[e], m0 = mt * 128;
        if (m0 >= cnte) continue;
        int off = 0;
        for (int ee = 0; ee < NE; ee++) off += (ee < e) ? cnt[ee] : 0;
        int n0 = ntl * 128;
        int rl = tid >> 1, half = tid & 1;
        int i = m0 + rl;
        if (i >= cnte) continue;
        int t = buck[e * T_TOK + i];
        int g = off + i;
        size_t colb = (size_t)n0 + half * 64;
        const float* p0 = part + (size_t)g * DM + colb;
        float* op = out + (size_t)t * DM + colb;
#pragma unroll
        for (int v = 0; v < 16; v++) {
            f32x4_t s = *(const f32x4_t*)&p0[v * 4];
            s += *(const f32x4_t*)&p0[(size_t)1 * T_TOK * DM + v * 4];
            s += *(const f32x4_t*)&p0[(size_t)2 * T_TOK * DM + v * 4];
            s += *(const f32x4_t*)&p0[(size_t)3 * T_TOK * DM + v * 4];
            f32x4_t o = *(const f32x4_t*)&op[v * 4];
            *(f32x4_t*)&op[v * 4] = o + s;
        }
    }
}

extern "C" void kernel_launch(void* const* d_in, const int* in_sizes, int n_in,
                              void* d_out, int out_size, void* d_ws, size_t ws_size,
                              hipStream_t stream) {
    const float* x    = (const float*)d_in[0];
    const float* ln1g = (const float*)d_in[1];
    const float* ln1b = (const float*)d_in[2];
    // d_in[3..6] = Wq,bq,Wk,bk: dead code
    const float* Wv   = (const float*)d_in[7];
    const float* bv   = (const float*)d_in[8];
    const float* ln2g = (const float*)d_in[9];
    const float* ln2b = (const float*)d_in[10];
    const float* Wg   = (const float*)d_in[11];
    const float* bg   = (const float*)d_in[12];
    const float* W1   = (const float*)d_in[13];
    const float* b1   = (const float*)d_in[14];
    const float* W2   = (const float*)d_in[15];
    const float* b2   = (const float*)d_in[16];

    char* ws = (char*)d_ws;
    int*   cnt  = (int*)(ws + OFF_CNT);
    int*   bars = (int*)(ws + OFF_BAR);
    int*   buck = (int*)(ws + OFF_BUCK);
    u16*   h2   = (u16*)(ws + OFF_H2);
    u16*   hmid = (u16*)(ws + OFF_HMID);
    float* part = (float*)(ws + OFF_PART);
    float* out  = (float*)d_out;

    hipMemsetAsync(ws, 0, 128, stream);
    k_mega<<<NBLK, 256, 0, stream>>>(x, ln1g, ln1b, Wv, bv, ln2g, ln2b, Wg, bg,
                                     W1, b1, W2, b2, cnt, bars, buck, h2, hmid,
                                     part, out);
}